// Round 11
// baseline (3694.604 us; speedup 1.0000x reference)
//
#include <hip/hip_runtime.h>

#define NB 256
#define NO 32
#define NEE 32
#define NT 16
#define THREADS 1024

typedef const float* __restrict__ fp;

struct Params {
  fp z;
  fp ee1w, ee1b, ee2w, ee2b, ee3w, ee3b;
  fp ne1w, ne1b, ne2w, ne2b, ne3w, ne3b, ne4w, ne4b;
  fp le1w, le1b, le2w, le2b, le3w, le3b;
  fp lt1w, lt1b, lt2w, lt2b, lt3w, lt3b, lt4w, lt4b, lt5w, lt5b;
  float* out;
  int tf;
};

__device__ __forceinline__ float frelu(float x) { return x > 0.f ? x : 0.f; }

// register-file broadcast: value of lane l (compile-time l after unroll)
__device__ __forceinline__ float rl(float v, int l) {
  return __uint_as_float(__builtin_amdgcn_readlane(__float_as_uint(v), l));
}

// LDS float offsets (16000 floats = 62.5 KiB static)
#define OFF_UT  0       // [64][33] u^T (+b1 folded), bank=(h+i)%32 conflict-free
#define OFF_VT  2112    // [64][33] v^T
#define OFF_AG  4224    // [32][64] agg row-major: atomics bank=lane%32 (2-way free)
#define OFF_BN  6272    // 2048: 16 waves x 128 bounce; doubles as A1 src [32][64]
#define OFF_NW  8320    // 7680: lt2(4096) lt3(2048) lt4(512) lt5(1024), resident
#define LDSF    16000

__device__ __forceinline__ void stageN(float* dst, const float* __restrict__ src,
                                       int nf4, int tid) {
  for (int i4 = tid; i4 < nf4; i4 += THREADS)
    *(float4*)(dst + i4 * 4) = *(const float4*)(src + i4 * 4);
}

// 2-row dense; w from GLOBAL (L2-hot, coalesced per-lane col) or LDS;
// x rows are LDS float4 broadcasts. One w read serves 2 rows.
template<int KC>
__device__ __forceinline__ void dense2L(const float* x0, const float* x1,
                                        const float* __restrict__ w, int ldw,
                                        int col, float o[2]) {
#pragma unroll 4
  for (int kc = 0; kc < KC; ++kc) {
    float w0 = w[(4 * kc + 0) * ldw + col];
    float w1 = w[(4 * kc + 1) * ldw + col];
    float w2 = w[(4 * kc + 2) * ldw + col];
    float w3 = w[(4 * kc + 3) * ldw + col];
    float4 a = *(const float4*)(x0 + 4 * kc);
    float4 b = *(const float4*)(x1 + 4 * kc);
    o[0] = fmaf(a.x, w0, o[0]); o[0] = fmaf(a.y, w1, o[0]); o[0] = fmaf(a.z, w2, o[0]); o[0] = fmaf(a.w, w3, o[0]);
    o[1] = fmaf(b.x, w0, o[1]); o[1] = fmaf(b.y, w1, o[1]); o[1] = fmaf(b.z, w2, o[1]); o[1] = fmaf(b.w, w3, o[1]);
  }
}

__global__ __launch_bounds__(THREADS) void rld_kernel(Params P) {
  __shared__ float lds[LDSF];
  const int b = blockIdx.x;
  const int tid = (int)threadIdx.x;
  const int lane = tid & 63;
  const int wave = tid >> 6;           // 0..15
  const int cc = lane & 31;
  const int c16 = lane & 15;

  float* UT = lds + OFF_UT;
  float* VT = lds + OFF_VT;
  float* AG = lds + OFF_AG;
  float* sBn = lds + OFF_BN + wave * 128;   // wave-private bounce (2 rows x 64)
  float* src = lds + OFF_BN;                // A1 only (before bounce use)
  const float* wlt2 = lds + OFF_NW;
  const float* wlt3 = lds + OFF_NW + 4096;
  const float* wlt4 = lds + OFF_NW + 6144;
  const float* wlt5 = lds + OFF_NW + 6656;
  const int i0 = wave, i1 = wave + 16;      // 2 rows per wave
  const int h33 = lane * 33;
  const float* zb = P.z + (size_t)b * NT * NO * NEE;

  // stage step-invariant small node weights once (read from s=1 on)
  stageN(lds + OFF_NW,        P.lt2w, 1024, tid);
  stageN(lds + OFF_NW + 4096, P.lt3w,  512, tid);
  stageN(lds + OFF_NW + 6144, P.lt4w,  128, tid);
  stageN(lds + OFF_NW + 6656, P.lt5w,  256, tid);

  // ===== A1: src[32,512] @ {ee1u, ee1v, ne1src}; 8 chunks of [32][64] =====
  float au[2] = {0,0}, av[2] = {0,0}, s1r[2] = {0,0};
  for (int qq = 0; qq < 8; ++qq) {
    __syncthreads();                    // prior chunk readers done
    for (int idx = tid; idx < 2048; idx += THREADS) {
      int i = idx >> 6, kk = idx & 63;
      int k = qq * 64 + kk, t = k >> 5, e = k & 31;
      float v = zb[(t * NO + i) * NEE + e];
      if (t > 0) v -= zb[((t - 1) * NO + i) * NEE + e];
      src[i * 64 + kk] = v;
    }
    __syncthreads();                    // chunk visible
    for (int c = 0; c < 2; ++c) {
      int r0 = qq * 64 + c * 32;
      const float* x0 = src + i0 * 64 + c * 32;
      const float* x1 = src + i1 * 64 + c * 32;
      dense2L<8>(x0, x1, P.ee1w + (size_t)r0 * 64,         64, lane, au);
      dense2L<8>(x0, x1, P.ee1w + (size_t)(512 + r0) * 64, 64, lane, av);
      dense2L<8>(x0, x1, P.ne1w + (size_t)r0 * 64,         64, lane, s1r);
    }
  }
  {
    float eb1 = P.ee1b[lane];           // fold b1 into u^T
    UT[h33 + i0] = au[0] + eb1; UT[h33 + i1] = au[1] + eb1;
    VT[h33 + i0] = av[0];      VT[h33 + i1] = av[1];
  }
  for (int z = tid; z < 2048; z += THREADS) AG[z] = 0.f;

  // pair-MLP weight COLUMNS in registers (lane = output channel)
  float w2c[64], w3c[64];
#pragma unroll
  for (int h = 0; h < 64; ++h) w2c[h] = P.ee2w[h * 64 + lane];
#pragma unroll
  for (int h = 0; h < 64; ++h) w3c[h] = P.ee3w[h * 64 + lane];
  float b2c = P.ee2b[lane], b3c = P.ee3b[lane];
  __syncthreads();                      // UT/VT/AG/NW published

  const int tf = P.tf;
  float zci[2] = {0, 0};
  float* outb = P.out + (size_t)b * tf * NO * NEE;

  for (int s = 0; s <= tf; ++s) {
    // ===== pair phase: 31 pairs/wave (496 = 16x31 exact); 15x2 + 1 =====
    {
      int pi = 0, rem = wave * 31;
      while (rem >= 31 - pi) { rem -= 31 - pi; ++pi; }   // unrank start (triu)
      int pj = pi + 1 + rem;
#pragma unroll 1
      for (int pp = 0; pp < 15; ++pp) {
        const int iA = pi, jA = pj;
        ++pj; if (pj == 32) { ++pi; pj = pi + 1; }
        const int iB = pi, jB = pj;
        ++pj; if (pj == 32) { ++pi; pj = pi + 1; }
        float xA = fmaxf(UT[h33 + iA] + VT[h33 + jA], 0.f);  // lane = h
        float xB = fmaxf(UT[h33 + iB] + VT[h33 + jB], 0.f);
        float a0 = b2c, a1 = 0.f, c0 = b2c, c1 = 0.f;
#pragma unroll
        for (int h = 0; h < 64; h += 2) {
          a0 = fmaf(rl(xA, h),     w2c[h],     a0);
          a1 = fmaf(rl(xA, h + 1), w2c[h + 1], a1);
          c0 = fmaf(rl(xB, h),     w2c[h],     c0);
          c1 = fmaf(rl(xB, h + 1), w2c[h + 1], c1);
        }
        float yA = fmaxf(a0 + a1, 0.f);                      // lane = h for L3
        float yB = fmaxf(c0 + c1, 0.f);
        float e0 = b3c, e1 = 0.f, f0 = b3c, f1 = 0.f;
#pragma unroll
        for (int h = 0; h < 64; h += 2) {
          e0 = fmaf(rl(yA, h),     w3c[h],     e0);
          e1 = fmaf(rl(yA, h + 1), w3c[h + 1], e1);
          f0 = fmaf(rl(yB, h),     w3c[h],     f0);
          f1 = fmaf(rl(yB, h + 1), w3c[h + 1], f1);
        }
        float eA = e0 + e1, eB = f0 + f1;
        atomicAdd(&AG[iA * 64 + lane],  eA);
        atomicAdd(&AG[jA * 64 + lane], -eA);
        atomicAdd(&AG[iB * 64 + lane],  eB);
        atomicAdd(&AG[jB * 64 + lane], -eB);
      }
      {   // epilogue: pair 30 of this wave
        const int iA = pi, jA = pj;
        float xA = fmaxf(UT[h33 + iA] + VT[h33 + jA], 0.f);
        float a0 = b2c, a1 = 0.f;
#pragma unroll
        for (int h = 0; h < 64; h += 2) {
          a0 = fmaf(rl(xA, h),     w2c[h],     a0);
          a1 = fmaf(rl(xA, h + 1), w2c[h + 1], a1);
        }
        float yA = fmaxf(a0 + a1, 0.f);
        float e0 = b3c, e1 = 0.f;
#pragma unroll
        for (int h = 0; h < 64; h += 2) {
          e0 = fmaf(rl(yA, h),     w3c[h],     e0);
          e1 = fmaf(rl(yA, h + 1), w3c[h + 1], e1);
        }
        float eA = e0 + e1;
        atomicAdd(&AG[iA * 64 + lane],  eA);
        atomicAdd(&AG[jA * 64 + lane], -eA);
      }
    }
    __syncthreads();                    // B1: agg complete

    if (s == 0) {
      // ----- ne node MLP -> zci -----
      float nb1 = P.ne1b[lane], nb2 = P.ne2b[lane];
      float nb3 = P.ne3b[cc],   nb4 = P.ne4b[cc];
      float o1[2] = {s1r[0] + nb1, s1r[1] + nb1};
      dense2L<16>(AG + i0 * 64, AG + i1 * 64, P.ne1w + (size_t)512 * 64, 64, lane, o1);
      sBn[lane] = frelu(o1[0]); sBn[64 + lane] = frelu(o1[1]);
      float o2[2] = {nb2, nb2};
      dense2L<16>(sBn, sBn + 64, P.ne2w, 64, lane, o2);
      sBn[lane] = frelu(o2[0]); sBn[64 + lane] = frelu(o2[1]);
      float o3[2] = {nb3, nb3};
      dense2L<16>(sBn, sBn + 64, P.ne3w, 32, cc, o3);
      sBn[cc] = frelu(o3[0]); sBn[64 + cc] = frelu(o3[1]);
      float o4[2] = {nb4, nb4};
      dense2L<8>(sBn, sBn + 64, P.ne4w, 32, cc, o4);
      zci[0] = (lane < 32) ? zb[(15 * NO + i0) * NEE + lane] : o4[0];
      zci[1] = (lane < 32) ? zb[(15 * NO + i1) * NEE + lane] : o4[1];
    } else {
      // ----- lt node MLP (sBn holds zci bounce from prep(s-1)) -----
      float lb1 = P.lt1b[lane], lb2 = P.lt2b[lane];
      float lb3 = P.lt3b[cc],   lb4 = P.lt4b[c16], lb5 = P.lt5b[lane];
      float o1[2] = {lb1, lb1};
      dense2L<16>(sBn, sBn + 64, P.lt1w, 64, lane, o1);
      dense2L<16>(AG + i0 * 64, AG + i1 * 64, P.lt1w + (size_t)64 * 64, 64, lane, o1);
      sBn[lane] = frelu(o1[0]); sBn[64 + lane] = frelu(o1[1]);
      float o2[2] = {lb2, lb2};
      dense2L<16>(sBn, sBn + 64, wlt2, 64, lane, o2);
      sBn[lane] = frelu(o2[0]); sBn[64 + lane] = frelu(o2[1]);
      float o3[2] = {lb3, lb3};
      dense2L<16>(sBn, sBn + 64, wlt3, 32, cc, o3);
      sBn[cc] = frelu(o3[0]); sBn[64 + cc] = frelu(o3[1]);
      float o4[2] = {lb4, lb4};
      dense2L<8>(sBn, sBn + 64, wlt4, 16, c16, o4);
      sBn[c16] = frelu(o4[0]); sBn[64 + c16] = frelu(o4[1]);
      float o5[2] = {lb5, lb5};
      dense2L<4>(sBn, sBn + 64, wlt5, 64, lane, o5);
      zci[0] += o5[0]; zci[1] += o5[1];
      int t = s - 1;
      if (lane < 32) {
        outb[(t * NO + i0) * NEE + lane] = zci[0];
        outb[(t * NO + i1) * NEE + lane] = zci[1];
      }
    }
    __syncthreads();                    // B2: AG readers done

    if (s < tf) {
      if (s == 0) {                     // switch pair weights ee -> le (once)
#pragma unroll
        for (int h = 0; h < 64; ++h) w2c[h] = P.le2w[h * 64 + lane];
#pragma unroll
        for (int h = 0; h < 64; ++h) w3c[h] = P.le3w[h * 64 + lane];
        b2c = P.le2b[lane]; b3c = P.le3b[lane];
      }
      for (int z = tid; z < 2048; z += THREADS) AG[z] = 0.f;
      sBn[lane] = zci[0]; sBn[64 + lane] = zci[1];
      float gb1 = P.le1b[lane];
      float ou[2] = {0,0}, ov[2] = {0,0};
      dense2L<16>(sBn, sBn + 64, P.le1w,        64, lane, ou);
      dense2L<16>(sBn, sBn + 64, P.le1w + 4096, 64, lane, ov);
      UT[h33 + i0] = ou[0] + gb1; UT[h33 + i1] = ou[1] + gb1;
      VT[h33 + i0] = ov[0];       VT[h33 + i1] = ov[1];
    }
    __syncthreads();                    // B3: UT/VT + agg-zero published
  }
}

extern "C" void kernel_launch(void* const* d_in, const int* in_sizes, int n_in,
                              void* d_out, int out_size, void* d_ws, size_t ws_size,
                              hipStream_t stream) {
  (void)in_sizes; (void)n_in; (void)d_ws; (void)ws_size;
  Params P;
  int q = 0;
  P.z    = (fp)d_in[q++];
  P.ee1w = (fp)d_in[q++]; P.ee1b = (fp)d_in[q++];
  P.ee2w = (fp)d_in[q++]; P.ee2b = (fp)d_in[q++];
  P.ee3w = (fp)d_in[q++]; P.ee3b = (fp)d_in[q++];
  P.ne1w = (fp)d_in[q++]; P.ne1b = (fp)d_in[q++];
  P.ne2w = (fp)d_in[q++]; P.ne2b = (fp)d_in[q++];
  P.ne3w = (fp)d_in[q++]; P.ne3b = (fp)d_in[q++];
  P.ne4w = (fp)d_in[q++]; P.ne4b = (fp)d_in[q++];
  P.le1w = (fp)d_in[q++]; P.le1b = (fp)d_in[q++];
  P.le2w = (fp)d_in[q++]; P.le2b = (fp)d_in[q++];
  P.le3w = (fp)d_in[q++]; P.le3b = (fp)d_in[q++];
  P.lt1w = (fp)d_in[q++]; P.lt1b = (fp)d_in[q++];
  P.lt2w = (fp)d_in[q++]; P.lt2b = (fp)d_in[q++];
  P.lt3w = (fp)d_in[q++]; P.lt3b = (fp)d_in[q++];
  P.lt4w = (fp)d_in[q++]; P.lt4b = (fp)d_in[q++];
  P.lt5w = (fp)d_in[q++]; P.lt5b = (fp)d_in[q++];
  P.out = (float*)d_out;
  P.tf = out_size / (NB * NO * NEE);
  if (P.tf < 1) P.tf = 1;
  hipLaunchKernelGGL(rld_kernel, dim3(NB), dim3(THREADS), 0, stream, P);
}

// Round 12
// 1598.026 us; speedup vs baseline: 2.3120x; 2.3120x over previous
//
#include <hip/hip_runtime.h>

#define NB 256
#define NO 32
#define NEE 32
#define NT 16
#define THREADS 512

typedef const float* __restrict__ fp;

struct Params {
  fp z;
  fp ee1w, ee1b, ee2w, ee2b, ee3w, ee3b;
  fp ne1w, ne1b, ne2w, ne2b, ne3w, ne3b, ne4w, ne4b;
  fp le1w, le1b, le2w, le2b, le3w, le3b;
  fp lt1w, lt1b, lt2w, lt2b, lt3w, lt3b, lt4w, lt4b, lt5w, lt5b;
  float* out;
  int tf;
};

__device__ __forceinline__ float frelu(float x) { return x > 0.f ? x : 0.f; }

// register-file broadcast: value of lane l (compile-time l after unroll)
__device__ __forceinline__ float rl(float v, int l) {
  return __uint_as_float(__builtin_amdgcn_readlane(__float_as_uint(v), l));
}

// LDS float offsets (12544 floats = 49 KiB static)
#define OFF_UT  0       // [64][33] u^T (+b1 folded), bank=(h+i)%32 conflict-free
#define OFF_VT  2112    // [64][33] v^T
#define OFF_AG  4224    // [32][64] agg row-major: atomics bank=lane%32 (2-way free)
#define OFF_BN  6272    // 2048: 8 waves x 256 bounce; doubles as A1 src [32][64]
#define OFF_W3T 8320    // [64][66] w3 transposed+padded: b64 row reads, 2-way free
#define LDSF    12544

// stage w3 [64][64] -> transposed padded W3T[c][h] (c*66+h)
__device__ __forceinline__ void stageW3T(float* lds, fp w3, int tid) {
#pragma unroll
  for (int r = 0; r < 8; ++r) {
    int idx = tid + r * THREADS;
    int h = idx >> 6, c = idx & 63;
    lds[OFF_W3T + c * 66 + h] = w3[h * 64 + c];
  }
}

// 4-row dense; w from GLOBAL (L2-hot, coalesced per-lane col);
// x rows are LDS float4 broadcasts. One w read serves 4 rows.
template<int KC>
__device__ __forceinline__ void dense4L(const float* x0, const float* x1,
                                        const float* x2, const float* x3,
                                        const float* __restrict__ w, int ldw,
                                        int col, float o[4]) {
#pragma unroll 4
  for (int kc = 0; kc < KC; ++kc) {
    float w0 = w[(4 * kc + 0) * ldw + col];
    float w1 = w[(4 * kc + 1) * ldw + col];
    float w2 = w[(4 * kc + 2) * ldw + col];
    float w3 = w[(4 * kc + 3) * ldw + col];
    float4 a = *(const float4*)(x0 + 4 * kc);
    float4 b = *(const float4*)(x1 + 4 * kc);
    float4 c = *(const float4*)(x2 + 4 * kc);
    float4 d = *(const float4*)(x3 + 4 * kc);
    o[0] = fmaf(a.x, w0, o[0]); o[0] = fmaf(a.y, w1, o[0]); o[0] = fmaf(a.z, w2, o[0]); o[0] = fmaf(a.w, w3, o[0]);
    o[1] = fmaf(b.x, w0, o[1]); o[1] = fmaf(b.y, w1, o[1]); o[1] = fmaf(b.z, w2, o[1]); o[1] = fmaf(b.w, w3, o[1]);
    o[2] = fmaf(c.x, w0, o[2]); o[2] = fmaf(c.y, w1, o[2]); o[2] = fmaf(c.z, w2, o[2]); o[2] = fmaf(c.w, w3, o[2]);
    o[3] = fmaf(d.x, w0, o[3]); o[3] = fmaf(d.y, w1, o[3]); o[3] = fmaf(d.z, w2, o[3]); o[3] = fmaf(d.w, w3, o[3]);
  }
}

__global__ __launch_bounds__(THREADS) void rld_kernel(Params P) {
  __shared__ float lds[LDSF];
  const int b = blockIdx.x;
  const int tid = (int)threadIdx.x;
  const int lane = tid & 63;
  const int wave = tid >> 6;
  const int cc = lane & 31;
  const int c16 = lane & 15;

  float* UT = lds + OFF_UT;
  float* VT = lds + OFF_VT;
  float* AG = lds + OFF_AG;
  float* sBn = lds + OFF_BN + wave * 256;   // wave-private bounce
  float* src = lds + OFF_BN;                // A1 only (before bounce use)
  const int i0 = wave, i1 = wave + 8, i2 = wave + 16, i3 = wave + 24;
  const int h33 = lane * 33;
  const float* zb = P.z + (size_t)b * NT * NO * NEE;

  // stage ee3 transposed (pair layer-3 weights for s=0)
  stageW3T(lds, P.ee3w, tid);

  // ===== A1: src[32,512] @ {ee1u, ee1v, ne1src}; 8 chunks of [32][64] =====
  float au[4] = {0,0,0,0}, av[4] = {0,0,0,0}, s1r[4] = {0,0,0,0};
  for (int qq = 0; qq < 8; ++qq) {
    __syncthreads();                    // prior chunk readers done
    for (int idx = tid; idx < 2048; idx += THREADS) {
      int i = idx >> 6, kk = idx & 63;
      int k = qq * 64 + kk, t = k >> 5, e = k & 31;
      float v = zb[(t * NO + i) * NEE + e];
      if (t > 0) v -= zb[((t - 1) * NO + i) * NEE + e];
      src[i * 64 + kk] = v;
    }
    __syncthreads();                    // chunk visible
    for (int c = 0; c < 2; ++c) {
      int r0 = qq * 64 + c * 32;
      const float* x0 = src + i0 * 64 + c * 32;
      const float* x1 = src + i1 * 64 + c * 32;
      const float* x2 = src + i2 * 64 + c * 32;
      const float* x3 = src + i3 * 64 + c * 32;
      dense4L<8>(x0, x1, x2, x3, P.ee1w + (size_t)r0 * 64,         64, lane, au);
      dense4L<8>(x0, x1, x2, x3, P.ee1w + (size_t)(512 + r0) * 64, 64, lane, av);
      dense4L<8>(x0, x1, x2, x3, P.ne1w + (size_t)r0 * 64,         64, lane, s1r);
    }
  }
  {
    float eb1 = P.ee1b[lane];           // fold b1 into u^T
    UT[h33 + i0] = au[0] + eb1; UT[h33 + i1] = au[1] + eb1;
    UT[h33 + i2] = au[2] + eb1; UT[h33 + i3] = au[3] + eb1;
    VT[h33 + i0] = av[0]; VT[h33 + i1] = av[1];
    VT[h33 + i2] = av[2]; VT[h33 + i3] = av[3];
  }
  for (int z = tid; z < 2048; z += THREADS) AG[z] = 0.f;

  // pair-MLP layer-2 weight COLUMNS in registers (lane = output channel)
  float w2c[64];
#pragma unroll
  for (int h = 0; h < 64; ++h) w2c[h] = P.ee2w[h * 64 + lane];
  float b2c = P.ee2b[lane], b3c = P.ee3b[lane];
  __syncthreads();                      // UT/VT/AG/W3T published

  const int tf = P.tf;
  float zci[4] = {0, 0, 0, 0};
  float* outb = P.out + (size_t)b * tf * NO * NEE;

  for (int s = 0; s <= tf; ++s) {
    // ===== pair phase: 62 pairs/wave, 2 at a time; L2 weights in regs,
    // L3 weights via ds_read_b64 from W3T (shared by both pairs) =====
    {
      int pi = 0, rem = wave * 62;
      while (rem >= 31 - pi) { rem -= 31 - pi; ++pi; }
      int pj = pi + 1 + rem;
      const float* w3row = lds + OFF_W3T + lane * 66;
#pragma unroll 1
      for (int pp = 0; pp < 31; ++pp) {
        const int iA = pi, jA = pj;
        ++pj; if (pj == 32) { ++pi; pj = pi + 1; }
        const int iB = pi, jB = pj;
        ++pj; if (pj == 32) { ++pi; pj = pi + 1; }
        float xA = fmaxf(UT[h33 + iA] + VT[h33 + jA], 0.f);  // lane = h
        float xB = fmaxf(UT[h33 + iB] + VT[h33 + jB], 0.f);
        float a0 = b2c, a1 = 0.f, c0 = b2c, c1 = 0.f;
#pragma unroll
        for (int h = 0; h < 64; h += 2) {
          a0 = fmaf(rl(xA, h),     w2c[h],     a0);
          a1 = fmaf(rl(xA, h + 1), w2c[h + 1], a1);
          c0 = fmaf(rl(xB, h),     w2c[h],     c0);
          c1 = fmaf(rl(xB, h + 1), w2c[h + 1], c1);
        }
        float yA = fmaxf(a0 + a1, 0.f);                      // lane = h for L3
        float yB = fmaxf(c0 + c1, 0.f);
        float e0 = b3c, e1 = 0.f, f0 = b3c, f1 = 0.f;
#pragma unroll
        for (int h = 0; h < 64; h += 2) {
          float2 wp = *(const float2*)(w3row + h);           // b64, 2-way free
          e0 = fmaf(rl(yA, h),     wp.x, e0);
          e1 = fmaf(rl(yA, h + 1), wp.y, e1);
          f0 = fmaf(rl(yB, h),     wp.x, f0);
          f1 = fmaf(rl(yB, h + 1), wp.y, f1);
        }
        float eA = e0 + e1, eB = f0 + f1;
        atomicAdd(&AG[iA * 64 + lane],  eA);
        atomicAdd(&AG[jA * 64 + lane], -eA);
        atomicAdd(&AG[iB * 64 + lane],  eB);
        atomicAdd(&AG[jB * 64 + lane], -eB);
      }
    }
    __syncthreads();                    // B1: agg complete

    if (s == 0) {
      // ----- ne node MLP -> zci -----
      float nb1 = P.ne1b[lane], nb2 = P.ne2b[lane];
      float nb3 = P.ne3b[cc],   nb4 = P.ne4b[cc];
      float o1[4] = {s1r[0] + nb1, s1r[1] + nb1, s1r[2] + nb1, s1r[3] + nb1};
      dense4L<16>(AG + i0 * 64, AG + i1 * 64, AG + i2 * 64, AG + i3 * 64,
                  P.ne1w + (size_t)512 * 64, 64, lane, o1);
      sBn[lane] = frelu(o1[0]); sBn[64 + lane] = frelu(o1[1]);
      sBn[128 + lane] = frelu(o1[2]); sBn[192 + lane] = frelu(o1[3]);
      float o2[4] = {nb2, nb2, nb2, nb2};
      dense4L<16>(sBn, sBn + 64, sBn + 128, sBn + 192, P.ne2w, 64, lane, o2);
      sBn[lane] = frelu(o2[0]); sBn[64 + lane] = frelu(o2[1]);
      sBn[128 + lane] = frelu(o2[2]); sBn[192 + lane] = frelu(o2[3]);
      float o3[4] = {nb3, nb3, nb3, nb3};
      dense4L<16>(sBn, sBn + 64, sBn + 128, sBn + 192, P.ne3w, 32, cc, o3);
      sBn[cc] = frelu(o3[0]); sBn[64 + cc] = frelu(o3[1]);
      sBn[128 + cc] = frelu(o3[2]); sBn[192 + cc] = frelu(o3[3]);
      float o4[4] = {nb4, nb4, nb4, nb4};
      dense4L<8>(sBn, sBn + 64, sBn + 128, sBn + 192, P.ne4w, 32, cc, o4);
      zci[0] = (lane < 32) ? zb[(15 * NO + i0) * NEE + lane] : o4[0];
      zci[1] = (lane < 32) ? zb[(15 * NO + i1) * NEE + lane] : o4[1];
      zci[2] = (lane < 32) ? zb[(15 * NO + i2) * NEE + lane] : o4[2];
      zci[3] = (lane < 32) ? zb[(15 * NO + i3) * NEE + lane] : o4[3];
    } else {
      // ----- lt node MLP (sBn holds zci bounce from prep(s-1)) -----
      float lb1 = P.lt1b[lane], lb2 = P.lt2b[lane];
      float lb3 = P.lt3b[cc],   lb4 = P.lt4b[c16], lb5 = P.lt5b[lane];
      float o1[4] = {lb1, lb1, lb1, lb1};
      dense4L<16>(sBn, sBn + 64, sBn + 128, sBn + 192, P.lt1w, 64, lane, o1);
      dense4L<16>(AG + i0 * 64, AG + i1 * 64, AG + i2 * 64, AG + i3 * 64,
                  P.lt1w + (size_t)64 * 64, 64, lane, o1);
      sBn[lane] = frelu(o1[0]); sBn[64 + lane] = frelu(o1[1]);
      sBn[128 + lane] = frelu(o1[2]); sBn[192 + lane] = frelu(o1[3]);
      float o2[4] = {lb2, lb2, lb2, lb2};
      dense4L<16>(sBn, sBn + 64, sBn + 128, sBn + 192, P.lt2w, 64, lane, o2);
      sBn[lane] = frelu(o2[0]); sBn[64 + lane] = frelu(o2[1]);
      sBn[128 + lane] = frelu(o2[2]); sBn[192 + lane] = frelu(o2[3]);
      float o3[4] = {lb3, lb3, lb3, lb3};
      dense4L<16>(sBn, sBn + 64, sBn + 128, sBn + 192, P.lt3w, 32, cc, o3);
      sBn[cc] = frelu(o3[0]); sBn[64 + cc] = frelu(o3[1]);
      sBn[128 + cc] = frelu(o3[2]); sBn[192 + cc] = frelu(o3[3]);
      float o4[4] = {lb4, lb4, lb4, lb4};
      dense4L<8>(sBn, sBn + 64, sBn + 128, sBn + 192, P.lt4w, 16, c16, o4);
      sBn[c16] = frelu(o4[0]); sBn[64 + c16] = frelu(o4[1]);
      sBn[128 + c16] = frelu(o4[2]); sBn[192 + c16] = frelu(o4[3]);
      float o5[4] = {lb5, lb5, lb5, lb5};
      dense4L<4>(sBn, sBn + 64, sBn + 128, sBn + 192, P.lt5w, 64, lane, o5);
      zci[0] += o5[0]; zci[1] += o5[1]; zci[2] += o5[2]; zci[3] += o5[3];
      int t = s - 1;
      if (lane < 32) {
        outb[(t * NO + i0) * NEE + lane] = zci[0];
        outb[(t * NO + i1) * NEE + lane] = zci[1];
        outb[(t * NO + i2) * NEE + lane] = zci[2];
        outb[(t * NO + i3) * NEE + lane] = zci[3];
      }
    }
    __syncthreads();                    // B2: AG readers done

    if (s < tf) {
      if (s == 0) {                     // switch pair weights ee -> le (once)
#pragma unroll
        for (int h = 0; h < 64; ++h) w2c[h] = P.le2w[h * 64 + lane];
        b2c = P.le2b[lane]; b3c = P.le3b[lane];
        stageW3T(lds, P.le3w, tid);     // W3T readers finished before B1
      }
      for (int z = tid; z < 2048; z += THREADS) AG[z] = 0.f;
      sBn[lane] = zci[0]; sBn[64 + lane] = zci[1];
      sBn[128 + lane] = zci[2]; sBn[192 + lane] = zci[3];
      float gb1 = P.le1b[lane];
      float ou[4] = {0,0,0,0}, ov[4] = {0,0,0,0};
      dense4L<16>(sBn, sBn + 64, sBn + 128, sBn + 192, P.le1w,        64, lane, ou);
      dense4L<16>(sBn, sBn + 64, sBn + 128, sBn + 192, P.le1w + 4096, 64, lane, ov);
      UT[h33 + i0] = ou[0] + gb1; UT[h33 + i1] = ou[1] + gb1;
      UT[h33 + i2] = ou[2] + gb1; UT[h33 + i3] = ou[3] + gb1;
      VT[h33 + i0] = ov[0]; VT[h33 + i1] = ov[1];
      VT[h33 + i2] = ov[2]; VT[h33 + i3] = ov[3];
    }
    __syncthreads();                    // B3: UT/VT + W3T + agg-zero published
  }
}

extern "C" void kernel_launch(void* const* d_in, const int* in_sizes, int n_in,
                              void* d_out, int out_size, void* d_ws, size_t ws_size,
                              hipStream_t stream) {
  (void)in_sizes; (void)n_in; (void)d_ws; (void)ws_size;
  Params P;
  int q = 0;
  P.z    = (fp)d_in[q++];
  P.ee1w = (fp)d_in[q++]; P.ee1b = (fp)d_in[q++];
  P.ee2w = (fp)d_in[q++]; P.ee2b = (fp)d_in[q++];
  P.ee3w = (fp)d_in[q++]; P.ee3b = (fp)d_in[q++];
  P.ne1w = (fp)d_in[q++]; P.ne1b = (fp)d_in[q++];
  P.ne2w = (fp)d_in[q++]; P.ne2b = (fp)d_in[q++];
  P.ne3w = (fp)d_in[q++]; P.ne3b = (fp)d_in[q++];
  P.ne4w = (fp)d_in[q++]; P.ne4b = (fp)d_in[q++];
  P.le1w = (fp)d_in[q++]; P.le1b = (fp)d_in[q++];
  P.le2w = (fp)d_in[q++]; P.le2b = (fp)d_in[q++];
  P.le3w = (fp)d_in[q++]; P.le3b = (fp)d_in[q++];
  P.lt1w = (fp)d_in[q++]; P.lt1b = (fp)d_in[q++];
  P.lt2w = (fp)d_in[q++]; P.lt2b = (fp)d_in[q++];
  P.lt3w = (fp)d_in[q++]; P.lt3b = (fp)d_in[q++];
  P.lt4w = (fp)d_in[q++]; P.lt4b = (fp)d_in[q++];
  P.lt5w = (fp)d_in[q++]; P.lt5b = (fp)d_in[q++];
  P.out = (float*)d_out;
  P.tf = out_size / (NB * NO * NEE);
  if (P.tf < 1) P.tf = 1;
  hipLaunchKernelGGL(rld_kernel, dim3(NB), dim3(THREADS), 0, stream, P);
}

// Round 13
// 1531.706 us; speedup vs baseline: 2.4121x; 1.0433x over previous
//
#include <hip/hip_runtime.h>

#define NB 256
#define NO 32
#define NEE 32
#define NT 16
#define THREADS 512

typedef const float* __restrict__ fp;

struct Params {
  fp z;
  fp ee1w, ee1b, ee2w, ee2b, ee3w, ee3b;
  fp ne1w, ne1b, ne2w, ne2b, ne3w, ne3b, ne4w, ne4b;
  fp le1w, le1b, le2w, le2b, le3w, le3b;
  fp lt1w, lt1b, lt2w, lt2b, lt3w, lt3b, lt4w, lt4b, lt5w, lt5b;
  float* out;
  int tf;
};

__device__ __forceinline__ float frelu(float x) { return x > 0.f ? x : 0.f; }

// register-file broadcast: value of lane l (compile-time l after unroll)
__device__ __forceinline__ float rl(float v, int l) {
  return __uint_as_float(__builtin_amdgcn_readlane(__float_as_uint(v), l));
}

// AGPR storage: w3 columns live in the accumulator file (unified RF on gfx950;
// AGPRs don't count against the 128-VGPR-class cap -> no scratch spill)
#define AGPR_WRITE(dst, src) asm("v_accvgpr_write_b32 %0, %1" : "=a"(dst) : "v"(src))
#define AGPR_READ(dst, src)  asm("v_accvgpr_read_b32 %0, %1"  : "=v"(dst) : "a"(src))

// LDS float offsets (8320 floats = 32.5 KiB static)
#define OFF_UT  0       // [64][33] u^T (+b1 folded), bank=(h+i)%32 conflict-free
#define OFF_VT  2112    // [64][33] v^T
#define OFF_AG  4224    // [32][64] agg row-major: atomics bank=lane%32 (2-way free)
#define OFF_BN  6272    // 2048: 8 waves x 256 bounce; doubles as A1 src [32][64]
#define LDSF    8320

// 4-row dense; w from GLOBAL (L2-hot, coalesced per-lane col);
// x rows are LDS float4 broadcasts. One w read serves 4 rows.
template<int KC>
__device__ __forceinline__ void dense4L(const float* x0, const float* x1,
                                        const float* x2, const float* x3,
                                        const float* __restrict__ w, int ldw,
                                        int col, float o[4]) {
#pragma unroll 4
  for (int kc = 0; kc < KC; ++kc) {
    float w0 = w[(4 * kc + 0) * ldw + col];
    float w1 = w[(4 * kc + 1) * ldw + col];
    float w2 = w[(4 * kc + 2) * ldw + col];
    float w3 = w[(4 * kc + 3) * ldw + col];
    float4 a = *(const float4*)(x0 + 4 * kc);
    float4 b = *(const float4*)(x1 + 4 * kc);
    float4 c = *(const float4*)(x2 + 4 * kc);
    float4 d = *(const float4*)(x3 + 4 * kc);
    o[0] = fmaf(a.x, w0, o[0]); o[0] = fmaf(a.y, w1, o[0]); o[0] = fmaf(a.z, w2, o[0]); o[0] = fmaf(a.w, w3, o[0]);
    o[1] = fmaf(b.x, w0, o[1]); o[1] = fmaf(b.y, w1, o[1]); o[1] = fmaf(b.z, w2, o[1]); o[1] = fmaf(b.w, w3, o[1]);
    o[2] = fmaf(c.x, w0, o[2]); o[2] = fmaf(c.y, w1, o[2]); o[2] = fmaf(c.z, w2, o[2]); o[2] = fmaf(c.w, w3, o[2]);
    o[3] = fmaf(d.x, w0, o[3]); o[3] = fmaf(d.y, w1, o[3]); o[3] = fmaf(d.z, w2, o[3]); o[3] = fmaf(d.w, w3, o[3]);
  }
}

__global__ __launch_bounds__(THREADS) void rld_kernel(Params P) {
  __shared__ float lds[LDSF];
  const int b = blockIdx.x;
  const int tid = (int)threadIdx.x;
  const int lane = tid & 63;
  const int wave = tid >> 6;
  const int cc = lane & 31;
  const int c16 = lane & 15;

  float* UT = lds + OFF_UT;
  float* VT = lds + OFF_VT;
  float* AG = lds + OFF_AG;
  float* sBn = lds + OFF_BN + wave * 256;   // wave-private bounce
  float* src = lds + OFF_BN;                // A1 only (before bounce use)
  const int i0 = wave, i1 = wave + 8, i2 = wave + 16, i3 = wave + 24;
  const int h33 = lane * 33;
  const float* zb = P.z + (size_t)b * NT * NO * NEE;

  // ===== A1: src[32,512] @ {ee1u, ee1v, ne1src}; 8 chunks of [32][64] =====
  float au[4] = {0,0,0,0}, av[4] = {0,0,0,0}, s1r[4] = {0,0,0,0};
  for (int qq = 0; qq < 8; ++qq) {
    __syncthreads();                    // prior chunk readers done
    for (int idx = tid; idx < 2048; idx += THREADS) {
      int i = idx >> 6, kk = idx & 63;
      int k = qq * 64 + kk, t = k >> 5, e = k & 31;
      float v = zb[(t * NO + i) * NEE + e];
      if (t > 0) v -= zb[((t - 1) * NO + i) * NEE + e];
      src[i * 64 + kk] = v;
    }
    __syncthreads();                    // chunk visible
    for (int c = 0; c < 2; ++c) {
      int r0 = qq * 64 + c * 32;
      const float* x0 = src + i0 * 64 + c * 32;
      const float* x1 = src + i1 * 64 + c * 32;
      const float* x2 = src + i2 * 64 + c * 32;
      const float* x3 = src + i3 * 64 + c * 32;
      dense4L<8>(x0, x1, x2, x3, P.ee1w + (size_t)r0 * 64,         64, lane, au);
      dense4L<8>(x0, x1, x2, x3, P.ee1w + (size_t)(512 + r0) * 64, 64, lane, av);
      dense4L<8>(x0, x1, x2, x3, P.ne1w + (size_t)r0 * 64,         64, lane, s1r);
    }
  }
  {
    float eb1 = P.ee1b[lane];           // fold b1 into u^T
    UT[h33 + i0] = au[0] + eb1; UT[h33 + i1] = au[1] + eb1;
    UT[h33 + i2] = au[2] + eb1; UT[h33 + i3] = au[3] + eb1;
    VT[h33 + i0] = av[0]; VT[h33 + i1] = av[1];
    VT[h33 + i2] = av[2]; VT[h33 + i3] = av[3];
  }
  for (int z = tid; z < 2048; z += THREADS) AG[z] = 0.f;

  // pair-MLP weights: layer-2 columns in VGPRs, layer-3 columns in AGPRs
  float w2c[64];
  float w3a[64];
#pragma unroll
  for (int h = 0; h < 64; ++h) w2c[h] = P.ee2w[h * 64 + lane];
#pragma unroll
  for (int h = 0; h < 64; ++h) {
    float v = P.ee3w[h * 64 + lane];
    AGPR_WRITE(w3a[h], v);
  }
  float b2c = P.ee2b[lane], b3c = P.ee3b[lane];
  __syncthreads();                      // UT/VT/AG published

  const int tf = P.tf;
  float zci[4] = {0, 0, 0, 0};
  float* outb = P.out + (size_t)b * tf * NO * NEE;

  for (int s = 0; s <= tf; ++s) {
    // ===== pair phase: 62 pairs/wave, 2 at a time; L2 weights in VGPRs,
    // L3 weights in AGPRs (one accvgpr_read serves both pairs); zero memory
    // in the FMA loops, zero spill (~95 VGPR-class live) =====
    {
      int pi = 0, rem = wave * 62;
      while (rem >= 31 - pi) { rem -= 31 - pi; ++pi; }
      int pj = pi + 1 + rem;
#pragma unroll 1
      for (int pp = 0; pp < 31; ++pp) {
        const int iA = pi, jA = pj;
        ++pj; if (pj == 32) { ++pi; pj = pi + 1; }
        const int iB = pi, jB = pj;
        ++pj; if (pj == 32) { ++pi; pj = pi + 1; }
        float xA = fmaxf(UT[h33 + iA] + VT[h33 + jA], 0.f);  // lane = h
        float xB = fmaxf(UT[h33 + iB] + VT[h33 + jB], 0.f);
        float a0 = b2c, a1 = 0.f, c0 = b2c, c1 = 0.f;
#pragma unroll
        for (int h = 0; h < 64; h += 2) {
          a0 = fmaf(rl(xA, h),     w2c[h],     a0);
          a1 = fmaf(rl(xA, h + 1), w2c[h + 1], a1);
          c0 = fmaf(rl(xB, h),     w2c[h],     c0);
          c1 = fmaf(rl(xB, h + 1), w2c[h + 1], c1);
        }
        float yA = fmaxf(a0 + a1, 0.f);                      // lane = h for L3
        float yB = fmaxf(c0 + c1, 0.f);
        float e0 = b3c, e1 = 0.f, f0 = b3c, f1 = 0.f;
#pragma unroll
        for (int h = 0; h < 64; h += 2) {
          float w0, w1;
          AGPR_READ(w0, w3a[h]);
          AGPR_READ(w1, w3a[h + 1]);
          e0 = fmaf(rl(yA, h),     w0, e0);
          e1 = fmaf(rl(yA, h + 1), w1, e1);
          f0 = fmaf(rl(yB, h),     w0, f0);
          f1 = fmaf(rl(yB, h + 1), w1, f1);
        }
        float eA = e0 + e1, eB = f0 + f1;
        atomicAdd(&AG[iA * 64 + lane],  eA);
        atomicAdd(&AG[jA * 64 + lane], -eA);
        atomicAdd(&AG[iB * 64 + lane],  eB);
        atomicAdd(&AG[jB * 64 + lane], -eB);
      }
    }
    __syncthreads();                    // B1: agg complete

    if (s == 0) {
      // ----- ne node MLP -> zci -----
      float nb1 = P.ne1b[lane], nb2 = P.ne2b[lane];
      float nb3 = P.ne3b[cc],   nb4 = P.ne4b[cc];
      float o1[4] = {s1r[0] + nb1, s1r[1] + nb1, s1r[2] + nb1, s1r[3] + nb1};
      dense4L<16>(AG + i0 * 64, AG + i1 * 64, AG + i2 * 64, AG + i3 * 64,
                  P.ne1w + (size_t)512 * 64, 64, lane, o1);
      sBn[lane] = frelu(o1[0]); sBn[64 + lane] = frelu(o1[1]);
      sBn[128 + lane] = frelu(o1[2]); sBn[192 + lane] = frelu(o1[3]);
      float o2[4] = {nb2, nb2, nb2, nb2};
      dense4L<16>(sBn, sBn + 64, sBn + 128, sBn + 192, P.ne2w, 64, lane, o2);
      sBn[lane] = frelu(o2[0]); sBn[64 + lane] = frelu(o2[1]);
      sBn[128 + lane] = frelu(o2[2]); sBn[192 + lane] = frelu(o2[3]);
      float o3[4] = {nb3, nb3, nb3, nb3};
      dense4L<16>(sBn, sBn + 64, sBn + 128, sBn + 192, P.ne3w, 32, cc, o3);
      sBn[cc] = frelu(o3[0]); sBn[64 + cc] = frelu(o3[1]);
      sBn[128 + cc] = frelu(o3[2]); sBn[192 + cc] = frelu(o3[3]);
      float o4[4] = {nb4, nb4, nb4, nb4};
      dense4L<8>(sBn, sBn + 64, sBn + 128, sBn + 192, P.ne4w, 32, cc, o4);
      zci[0] = (lane < 32) ? zb[(15 * NO + i0) * NEE + lane] : o4[0];
      zci[1] = (lane < 32) ? zb[(15 * NO + i1) * NEE + lane] : o4[1];
      zci[2] = (lane < 32) ? zb[(15 * NO + i2) * NEE + lane] : o4[2];
      zci[3] = (lane < 32) ? zb[(15 * NO + i3) * NEE + lane] : o4[3];
    } else {
      // ----- lt node MLP (sBn holds zci bounce from prep(s-1)) -----
      float lb1 = P.lt1b[lane], lb2 = P.lt2b[lane];
      float lb3 = P.lt3b[cc],   lb4 = P.lt4b[c16], lb5 = P.lt5b[lane];
      float o1[4] = {lb1, lb1, lb1, lb1};
      dense4L<16>(sBn, sBn + 64, sBn + 128, sBn + 192, P.lt1w, 64, lane, o1);
      dense4L<16>(AG + i0 * 64, AG + i1 * 64, AG + i2 * 64, AG + i3 * 64,
                  P.lt1w + (size_t)64 * 64, 64, lane, o1);
      sBn[lane] = frelu(o1[0]); sBn[64 + lane] = frelu(o1[1]);
      sBn[128 + lane] = frelu(o1[2]); sBn[192 + lane] = frelu(o1[3]);
      float o2[4] = {lb2, lb2, lb2, lb2};
      dense4L<16>(sBn, sBn + 64, sBn + 128, sBn + 192, P.lt2w, 64, lane, o2);
      sBn[lane] = frelu(o2[0]); sBn[64 + lane] = frelu(o2[1]);
      sBn[128 + lane] = frelu(o2[2]); sBn[192 + lane] = frelu(o2[3]);
      float o3[4] = {lb3, lb3, lb3, lb3};
      dense4L<16>(sBn, sBn + 64, sBn + 128, sBn + 192, P.lt3w, 32, cc, o3);
      sBn[cc] = frelu(o3[0]); sBn[64 + cc] = frelu(o3[1]);
      sBn[128 + cc] = frelu(o3[2]); sBn[192 + cc] = frelu(o3[3]);
      float o4[4] = {lb4, lb4, lb4, lb4};
      dense4L<8>(sBn, sBn + 64, sBn + 128, sBn + 192, P.lt4w, 16, c16, o4);
      sBn[c16] = frelu(o4[0]); sBn[64 + c16] = frelu(o4[1]);
      sBn[128 + c16] = frelu(o4[2]); sBn[192 + c16] = frelu(o4[3]);
      float o5[4] = {lb5, lb5, lb5, lb5};
      dense4L<4>(sBn, sBn + 64, sBn + 128, sBn + 192, P.lt5w, 64, lane, o5);
      zci[0] += o5[0]; zci[1] += o5[1]; zci[2] += o5[2]; zci[3] += o5[3];
      int t = s - 1;
      if (lane < 32) {
        outb[(t * NO + i0) * NEE + lane] = zci[0];
        outb[(t * NO + i1) * NEE + lane] = zci[1];
        outb[(t * NO + i2) * NEE + lane] = zci[2];
        outb[(t * NO + i3) * NEE + lane] = zci[3];
      }
    }
    __syncthreads();                    // B2: AG readers done

    if (s < tf) {
      if (s == 0) {                     // switch pair weights ee -> le (once)
#pragma unroll
        for (int h = 0; h < 64; ++h) w2c[h] = P.le2w[h * 64 + lane];
#pragma unroll
        for (int h = 0; h < 64; ++h) {
          float v = P.le3w[h * 64 + lane];
          AGPR_WRITE(w3a[h], v);
        }
        b2c = P.le2b[lane]; b3c = P.le3b[lane];
      }
      for (int z = tid; z < 2048; z += THREADS) AG[z] = 0.f;
      sBn[lane] = zci[0]; sBn[64 + lane] = zci[1];
      sBn[128 + lane] = zci[2]; sBn[192 + lane] = zci[3];
      float gb1 = P.le1b[lane];
      float ou[4] = {0,0,0,0}, ov[4] = {0,0,0,0};
      dense4L<16>(sBn, sBn + 64, sBn + 128, sBn + 192, P.le1w,        64, lane, ou);
      dense4L<16>(sBn, sBn + 64, sBn + 128, sBn + 192, P.le1w + 4096, 64, lane, ov);
      UT[h33 + i0] = ou[0] + gb1; UT[h33 + i1] = ou[1] + gb1;
      UT[h33 + i2] = ou[2] + gb1; UT[h33 + i3] = ou[3] + gb1;
      VT[h33 + i0] = ov[0]; VT[h33 + i1] = ov[1];
      VT[h33 + i2] = ov[2]; VT[h33 + i3] = ov[3];
    }
    __syncthreads();                    // B3: UT/VT + agg-zero published
  }
}

extern "C" void kernel_launch(void* const* d_in, const int* in_sizes, int n_in,
                              void* d_out, int out_size, void* d_ws, size_t ws_size,
                              hipStream_t stream) {
  (void)in_sizes; (void)n_in; (void)d_ws; (void)ws_size;
  Params P;
  int q = 0;
  P.z    = (fp)d_in[q++];
  P.ee1w = (fp)d_in[q++]; P.ee1b = (fp)d_in[q++];
  P.ee2w = (fp)d_in[q++]; P.ee2b = (fp)d_in[q++];
  P.ee3w = (fp)d_in[q++]; P.ee3b = (fp)d_in[q++];
  P.ne1w = (fp)d_in[q++]; P.ne1b = (fp)d_in[q++];
  P.ne2w = (fp)d_in[q++]; P.ne2b = (fp)d_in[q++];
  P.ne3w = (fp)d_in[q++]; P.ne3b = (fp)d_in[q++];
  P.ne4w = (fp)d_in[q++]; P.ne4b = (fp)d_in[q++];
  P.le1w = (fp)d_in[q++]; P.le1b = (fp)d_in[q++];
  P.le2w = (fp)d_in[q++]; P.le2b = (fp)d_in[q++];
  P.le3w = (fp)d_in[q++]; P.le3b = (fp)d_in[q++];
  P.lt1w = (fp)d_in[q++]; P.lt1b = (fp)d_in[q++];
  P.lt2w = (fp)d_in[q++]; P.lt2b = (fp)d_in[q++];
  P.lt3w = (fp)d_in[q++]; P.lt3b = (fp)d_in[q++];
  P.lt4w = (fp)d_in[q++]; P.lt4b = (fp)d_in[q++];
  P.lt5w = (fp)d_in[q++]; P.lt5b = (fp)d_in[q++];
  P.out = (float*)d_out;
  P.tf = out_size / (NB * NO * NEE);
  if (P.tf < 1) P.tf = 1;
  hipLaunchKernelGGL(rld_kernel, dim3(NB), dim3(THREADS), 0, stream, P);
}

// Round 14
// 1044.018 us; speedup vs baseline: 3.5388x; 1.4671x over previous
//
#include <hip/hip_runtime.h>

#define NB 256
#define NO 32
#define NEE 32
#define NT 16
#define THREADS 512

typedef const float* __restrict__ fp;

struct Params {
  fp z;
  fp ee1w, ee1b, ee2w, ee2b, ee3w, ee3b;
  fp ne1w, ne1b, ne2w, ne2b, ne3w, ne3b, ne4w, ne4b;
  fp le1w, le1b, le2w, le2b, le3w, le3b;
  fp lt1w, lt1b, lt2w, lt2b, lt3w, lt3b, lt4w, lt4b, lt5w, lt5b;
  float* out;
  int tf;
};

__device__ __forceinline__ float frelu(float x) { return x > 0.f ? x : 0.f; }

// register-file broadcast: value of lane l (compile-time l after unroll)
__device__ __forceinline__ float rl(float v, int l) {
  return __uint_as_float(__builtin_amdgcn_readlane(__float_as_uint(v), l));
}

// LDS float offsets (10368 floats = 40.5 KiB static)
#define OFF_UT  0       // [64][33] u^T (+b1 folded), bank=(h+i)%32 conflict-free
#define OFF_VT  2112    // [64][33] v^T
#define OFF_AG  4224    // [32][64] agg row-major: atomics bank=lane%32 (2-way free)
#define OFF_BN  6272    // 2048: 8 waves x 256 bounce; doubles as A1 src [32][64]
#define OFF_ZC  8320    // 2048: 8 waves x 256 wave-private stash (s1r / zci)
#define LDSF    10368

// 4-row dense; w from GLOBAL (L2-hot, coalesced per-lane col);
// x rows are LDS float4 broadcasts. One w read serves 4 rows.
template<int KC>
__device__ __forceinline__ void dense4L(const float* x0, const float* x1,
                                        const float* x2, const float* x3,
                                        const float* __restrict__ w, int ldw,
                                        int col, float o[4]) {
#pragma unroll 4
  for (int kc = 0; kc < KC; ++kc) {
    float w0 = w[(4 * kc + 0) * ldw + col];
    float w1 = w[(4 * kc + 1) * ldw + col];
    float w2 = w[(4 * kc + 2) * ldw + col];
    float w3 = w[(4 * kc + 3) * ldw + col];
    float4 a = *(const float4*)(x0 + 4 * kc);
    float4 b = *(const float4*)(x1 + 4 * kc);
    float4 c = *(const float4*)(x2 + 4 * kc);
    float4 d = *(const float4*)(x3 + 4 * kc);
    o[0] = fmaf(a.x, w0, o[0]); o[0] = fmaf(a.y, w1, o[0]); o[0] = fmaf(a.z, w2, o[0]); o[0] = fmaf(a.w, w3, o[0]);
    o[1] = fmaf(b.x, w0, o[1]); o[1] = fmaf(b.y, w1, o[1]); o[1] = fmaf(b.z, w2, o[1]); o[1] = fmaf(b.w, w3, o[1]);
    o[2] = fmaf(c.x, w0, o[2]); o[2] = fmaf(c.y, w1, o[2]); o[2] = fmaf(c.z, w2, o[2]); o[2] = fmaf(c.w, w3, o[2]);
    o[3] = fmaf(d.x, w0, o[3]); o[3] = fmaf(d.y, w1, o[3]); o[3] = fmaf(d.z, w2, o[3]); o[3] = fmaf(d.w, w3, o[3]);
  }
}

__global__ __launch_bounds__(THREADS) void rld_kernel(Params P) {
  __shared__ float lds[LDSF];
  const int b = blockIdx.x;
  const int tid = (int)threadIdx.x;
  const int lane = tid & 63;
  const int wave = tid >> 6;
  const int cc = lane & 31;
  const int c16 = lane & 15;

  float* UT = lds + OFF_UT;
  float* VT = lds + OFF_VT;
  float* AG = lds + OFF_AG;
  float* sBn = lds + OFF_BN + wave * 256;   // wave-private bounce
  float* ZC  = lds + OFF_ZC + wave * 256;   // wave-private stash
  float* src = lds + OFF_BN;                // A1 only (before bounce use)
  const int i0 = wave, i1 = wave + 8, i2 = wave + 16, i3 = wave + 24;
  const int h33 = lane * 33;
  const float* zb = P.z + (size_t)b * NT * NO * NEE;

  // ===== A1: src[32,512] @ {ee1u, ee1v, ne1src}; 8 chunks of [32][64] =====
  float au[4] = {0,0,0,0}, av[4] = {0,0,0,0}, s1r[4] = {0,0,0,0};
  for (int qq = 0; qq < 8; ++qq) {
    __syncthreads();                    // prior chunk readers done
    for (int idx = tid; idx < 2048; idx += THREADS) {
      int i = idx >> 6, kk = idx & 63;
      int k = qq * 64 + kk, t = k >> 5, e = k & 31;
      float v = zb[(t * NO + i) * NEE + e];
      if (t > 0) v -= zb[((t - 1) * NO + i) * NEE + e];
      src[i * 64 + kk] = v;
    }
    __syncthreads();                    // chunk visible
    for (int c = 0; c < 2; ++c) {
      int r0 = qq * 64 + c * 32;
      const float* x0 = src + i0 * 64 + c * 32;
      const float* x1 = src + i1 * 64 + c * 32;
      const float* x2 = src + i2 * 64 + c * 32;
      const float* x3 = src + i3 * 64 + c * 32;
      dense4L<8>(x0, x1, x2, x3, P.ee1w + (size_t)r0 * 64,         64, lane, au);
      dense4L<8>(x0, x1, x2, x3, P.ee1w + (size_t)(512 + r0) * 64, 64, lane, av);
      dense4L<8>(x0, x1, x2, x3, P.ne1w + (size_t)r0 * 64,         64, lane, s1r);
    }
  }
  __syncthreads();                      // src region readers done (ZC overlaps it? no: ZC separate)
  {
    float eb1 = P.ee1b[lane];           // fold b1 into u^T
    UT[h33 + i0] = au[0] + eb1; UT[h33 + i1] = au[1] + eb1;
    UT[h33 + i2] = au[2] + eb1; UT[h33 + i3] = au[3] + eb1;
    VT[h33 + i0] = av[0]; VT[h33 + i1] = av[1];
    VT[h33 + i2] = av[2]; VT[h33 + i3] = av[3];
    ZC[lane] = s1r[0]; ZC[64 + lane] = s1r[1];          // stash s1r (wave-private)
    ZC[128 + lane] = s1r[2]; ZC[192 + lane] = s1r[3];
  }
  for (int z = tid; z < 2048; z += THREADS) AG[z] = 0.f;

  // pair-MLP weight COLUMNS in registers (lane = output channel)
  float w2c[64], w3c[64];
#pragma unroll
  for (int h = 0; h < 64; ++h) w2c[h] = P.ee2w[h * 64 + lane];
#pragma unroll
  for (int h = 0; h < 64; ++h) w3c[h] = P.ee3w[h * 64 + lane];
  float b2c = P.ee2b[lane], b3c = P.ee3b[lane];
  __syncthreads();                      // UT/VT/AG published

  const int tf = P.tf;
  float* outb = P.out + (size_t)b * tf * NO * NEE;

  for (int s = 0; s <= tf; ++s) {
    // ===== pair phase: 62 pairs/wave, 2 in flight; gathers software-pipelined
    // one dual-pair ahead; readlanes batched 8-wide before their FMAs =====
    {
      int pi = 0, rem = wave * 62;
      while (rem >= 31 - pi) { rem -= 31 - pi; ++pi; }
      int pj = pi + 1 + rem;
      int iA = pi, jA = pj;
      ++pj; if (pj == 32) { ++pi; pj = pi + 1; }
      int iB = pi, jB = pj;
      ++pj; if (pj == 32) { ++pi; pj = pi + 1; }
      float uA = UT[h33 + iA], vA = VT[h33 + jA];
      float uB = UT[h33 + iB], vB = VT[h33 + jB];
#pragma unroll 1
      for (int pp = 0; pp < 31; ++pp) {
        const int aI = iA, aJ = jA, bI = iB, bJ = jB;
        float xA = fmaxf(uA + vA, 0.f);                    // lane = h
        float xB = fmaxf(uB + vB, 0.f);
        if (pp < 30) {                  // prefetch next dual-pair (hides ~120cy)
          iA = pi; jA = pj;
          ++pj; if (pj == 32) { ++pi; pj = pi + 1; }
          iB = pi; jB = pj;
          ++pj; if (pj == 32) { ++pi; pj = pi + 1; }
          uA = UT[h33 + iA]; vA = VT[h33 + jA];
          uB = UT[h33 + iB]; vB = VT[h33 + jB];
        }
        float a0 = b2c, a1 = 0.f, c0 = b2c, c1 = 0.f;
#pragma unroll
        for (int h = 0; h < 64; h += 4) {
          float r0 = rl(xA, h),     r1 = rl(xA, h + 1);
          float r2 = rl(xA, h + 2), r3 = rl(xA, h + 3);
          float s0 = rl(xB, h),     s1 = rl(xB, h + 1);
          float s2 = rl(xB, h + 2), s3 = rl(xB, h + 3);
          a0 = fmaf(r0, w2c[h],     a0); a1 = fmaf(r1, w2c[h + 1], a1);
          a0 = fmaf(r2, w2c[h + 2], a0); a1 = fmaf(r3, w2c[h + 3], a1);
          c0 = fmaf(s0, w2c[h],     c0); c1 = fmaf(s1, w2c[h + 1], c1);
          c0 = fmaf(s2, w2c[h + 2], c0); c1 = fmaf(s3, w2c[h + 3], c1);
        }
        float yA = fmaxf(a0 + a1, 0.f);                    // lane = h for L3
        float yB = fmaxf(c0 + c1, 0.f);
        float e0 = b3c, e1 = 0.f, f0 = b3c, f1 = 0.f;
#pragma unroll
        for (int h = 0; h < 64; h += 4) {
          float r0 = rl(yA, h),     r1 = rl(yA, h + 1);
          float r2 = rl(yA, h + 2), r3 = rl(yA, h + 3);
          float s0 = rl(yB, h),     s1 = rl(yB, h + 1);
          float s2 = rl(yB, h + 2), s3 = rl(yB, h + 3);
          e0 = fmaf(r0, w3c[h],     e0); e1 = fmaf(r1, w3c[h + 1], e1);
          e0 = fmaf(r2, w3c[h + 2], e0); e1 = fmaf(r3, w3c[h + 3], e1);
          f0 = fmaf(s0, w3c[h],     f0); f1 = fmaf(s1, w3c[h + 1], f1);
          f0 = fmaf(s2, w3c[h + 2], f0); f1 = fmaf(s3, w3c[h + 3], f1);
        }
        float eA = e0 + e1, eB = f0 + f1;
        if (aI == bI) {                 // wave-uniform; triu walk: usually same row
          atomicAdd(&AG[aI * 64 + lane], eA + eB);
        } else {
          atomicAdd(&AG[aI * 64 + lane], eA);
          atomicAdd(&AG[bI * 64 + lane], eB);
        }
        atomicAdd(&AG[aJ * 64 + lane], -eA);
        atomicAdd(&AG[bJ * 64 + lane], -eB);
      }
    }
    __syncthreads();                    // B1: agg complete

    float zn0, zn1, zn2, zn3;           // new zc (live node->prep only)
    if (s == 0) {
      // ----- ne node MLP -> zn -----
      float nb1 = P.ne1b[lane], nb2 = P.ne2b[lane];
      float nb3 = P.ne3b[cc],   nb4 = P.ne4b[cc];
      float o1[4] = {ZC[lane] + nb1, ZC[64 + lane] + nb1,
                     ZC[128 + lane] + nb1, ZC[192 + lane] + nb1};
      dense4L<16>(AG + i0 * 64, AG + i1 * 64, AG + i2 * 64, AG + i3 * 64,
                  P.ne1w + (size_t)512 * 64, 64, lane, o1);
      sBn[lane] = frelu(o1[0]); sBn[64 + lane] = frelu(o1[1]);
      sBn[128 + lane] = frelu(o1[2]); sBn[192 + lane] = frelu(o1[3]);
      float o2[4] = {nb2, nb2, nb2, nb2};
      dense4L<16>(sBn, sBn + 64, sBn + 128, sBn + 192, P.ne2w, 64, lane, o2);
      sBn[lane] = frelu(o2[0]); sBn[64 + lane] = frelu(o2[1]);
      sBn[128 + lane] = frelu(o2[2]); sBn[192 + lane] = frelu(o2[3]);
      float o3[4] = {nb3, nb3, nb3, nb3};
      dense4L<16>(sBn, sBn + 64, sBn + 128, sBn + 192, P.ne3w, 32, cc, o3);
      sBn[cc] = frelu(o3[0]); sBn[64 + cc] = frelu(o3[1]);
      sBn[128 + cc] = frelu(o3[2]); sBn[192 + cc] = frelu(o3[3]);
      float o4[4] = {nb4, nb4, nb4, nb4};
      dense4L<8>(sBn, sBn + 64, sBn + 128, sBn + 192, P.ne4w, 32, cc, o4);
      zn0 = (lane < 32) ? zb[(15 * NO + i0) * NEE + lane] : o4[0];
      zn1 = (lane < 32) ? zb[(15 * NO + i1) * NEE + lane] : o4[1];
      zn2 = (lane < 32) ? zb[(15 * NO + i2) * NEE + lane] : o4[2];
      zn3 = (lane < 32) ? zb[(15 * NO + i3) * NEE + lane] : o4[3];
    } else {
      // ----- lt node MLP (sBn holds zc bounce from prep(s-1)) -----
      float lb1 = P.lt1b[lane], lb2 = P.lt2b[lane];
      float lb3 = P.lt3b[cc],   lb4 = P.lt4b[c16], lb5 = P.lt5b[lane];
      float o1[4] = {lb1, lb1, lb1, lb1};
      dense4L<16>(sBn, sBn + 64, sBn + 128, sBn + 192, P.lt1w, 64, lane, o1);
      dense4L<16>(AG + i0 * 64, AG + i1 * 64, AG + i2 * 64, AG + i3 * 64,
                  P.lt1w + (size_t)64 * 64, 64, lane, o1);
      sBn[lane] = frelu(o1[0]); sBn[64 + lane] = frelu(o1[1]);
      sBn[128 + lane] = frelu(o1[2]); sBn[192 + lane] = frelu(o1[3]);
      float o2[4] = {lb2, lb2, lb2, lb2};
      dense4L<16>(sBn, sBn + 64, sBn + 128, sBn + 192, P.lt2w, 64, lane, o2);
      sBn[lane] = frelu(o2[0]); sBn[64 + lane] = frelu(o2[1]);
      sBn[128 + lane] = frelu(o2[2]); sBn[192 + lane] = frelu(o2[3]);
      float o3[4] = {lb3, lb3, lb3, lb3};
      dense4L<16>(sBn, sBn + 64, sBn + 128, sBn + 192, P.lt3w, 32, cc, o3);
      sBn[cc] = frelu(o3[0]); sBn[64 + cc] = frelu(o3[1]);
      sBn[128 + cc] = frelu(o3[2]); sBn[192 + cc] = frelu(o3[3]);
      float o4[4] = {lb4, lb4, lb4, lb4};
      dense4L<8>(sBn, sBn + 64, sBn + 128, sBn + 192, P.lt4w, 16, c16, o4);
      sBn[c16] = frelu(o4[0]); sBn[64 + c16] = frelu(o4[1]);
      sBn[128 + c16] = frelu(o4[2]); sBn[192 + c16] = frelu(o4[3]);
      float o5[4] = {lb5, lb5, lb5, lb5};
      dense4L<4>(sBn, sBn + 64, sBn + 128, sBn + 192, P.lt5w, 64, lane, o5);
      zn0 = ZC[lane] + o5[0];        zn1 = ZC[64 + lane] + o5[1];
      zn2 = ZC[128 + lane] + o5[2];  zn3 = ZC[192 + lane] + o5[3];
      int t = s - 1;
      if (lane < 32) {
        outb[(t * NO + i0) * NEE + lane] = zn0;
        outb[(t * NO + i1) * NEE + lane] = zn1;
        outb[(t * NO + i2) * NEE + lane] = zn2;
        outb[(t * NO + i3) * NEE + lane] = zn3;
      }
    }
    __syncthreads();                    // B2: AG readers done

    if (s < tf) {
      if (s == 0) {                     // switch pair weights ee -> le (once)
#pragma unroll
        for (int h = 0; h < 64; ++h) w2c[h] = P.le2w[h * 64 + lane];
#pragma unroll
        for (int h = 0; h < 64; ++h) w3c[h] = P.le3w[h * 64 + lane];
        b2c = P.le2b[lane]; b3c = P.le3b[lane];
      }
      for (int z = tid; z < 2048; z += THREADS) AG[z] = 0.f;
      sBn[lane] = zn0; sBn[64 + lane] = zn1;           // zc bounce for le1/lt1
      sBn[128 + lane] = zn2; sBn[192 + lane] = zn3;
      ZC[lane] = zn0; ZC[64 + lane] = zn1;             // stash (survives pair)
      ZC[128 + lane] = zn2; ZC[192 + lane] = zn3;
      float gb1 = P.le1b[lane];
      float ou[4] = {0,0,0,0}, ov[4] = {0,0,0,0};
      dense4L<16>(sBn, sBn + 64, sBn + 128, sBn + 192, P.le1w,        64, lane, ou);
      dense4L<16>(sBn, sBn + 64, sBn + 128, sBn + 192, P.le1w + 4096, 64, lane, ov);
      UT[h33 + i0] = ou[0] + gb1; UT[h33 + i1] = ou[1] + gb1;
      UT[h33 + i2] = ou[2] + gb1; UT[h33 + i3] = ou[3] + gb1;
      VT[h33 + i0] = ov[0]; VT[h33 + i1] = ov[1];
      VT[h33 + i2] = ov[2]; VT[h33 + i3] = ov[3];
    }
    __syncthreads();                    // B3: UT/VT + agg-zero published
  }
}

extern "C" void kernel_launch(void* const* d_in, const int* in_sizes, int n_in,
                              void* d_out, int out_size, void* d_ws, size_t ws_size,
                              hipStream_t stream) {
  (void)in_sizes; (void)n_in; (void)d_ws; (void)ws_size;
  Params P;
  int q = 0;
  P.z    = (fp)d_in[q++];
  P.ee1w = (fp)d_in[q++]; P.ee1b = (fp)d_in[q++];
  P.ee2w = (fp)d_in[q++]; P.ee2b = (fp)d_in[q++];
  P.ee3w = (fp)d_in[q++]; P.ee3b = (fp)d_in[q++];
  P.ne1w = (fp)d_in[q++]; P.ne1b = (fp)d_in[q++];
  P.ne2w = (fp)d_in[q++]; P.ne2b = (fp)d_in[q++];
  P.ne3w = (fp)d_in[q++]; P.ne3b = (fp)d_in[q++];
  P.ne4w = (fp)d_in[q++]; P.ne4b = (fp)d_in[q++];
  P.le1w = (fp)d_in[q++]; P.le1b = (fp)d_in[q++];
  P.le2w = (fp)d_in[q++]; P.le2b = (fp)d_in[q++];
  P.le3w = (fp)d_in[q++]; P.le3b = (fp)d_in[q++];
  P.lt1w = (fp)d_in[q++]; P.lt1b = (fp)d_in[q++];
  P.lt2w = (fp)d_in[q++]; P.lt2b = (fp)d_in[q++];
  P.lt3w = (fp)d_in[q++]; P.lt3b = (fp)d_in[q++];
  P.lt4w = (fp)d_in[q++]; P.lt4b = (fp)d_in[q++];
  P.lt5w = (fp)d_in[q++]; P.lt5b = (fp)d_in[q++];
  P.out = (float*)d_out;
  P.tf = out_size / (NB * NO * NEE);
  if (P.tf < 1) P.tf = 1;
  hipLaunchKernelGGL(rld_kernel, dim3(NB), dim3(THREADS), 0, stream, P);
}